// Round 1
// baseline (332.246 us; speedup 1.0000x reference)
//
#include <hip/hip_runtime.h>

// Problem constants
#define N_NODES 25000
#define N_EDGES 200000
// MUL=16, NUM_RADIAL=8, HIDDEN=64, WNUMEL=1024
// PATH_ALPHA=1/sqrt(32), INV_SQRT3=1/sqrt(3), scales folded into B-fragments.

constexpr int ET = 32;       // edges per tile
constexpr int NTILES = 6250; // 200000/32
constexpr int NBLK = 512;    // persistent grid; tiles strided by NBLK
constexpr int PL = ET * 17;  // coef/xch plane stride (544)

typedef __attribute__((ext_vector_type(8))) _Float16 half8;  // 8 f16 (4 VGPR)
typedef __attribute__((ext_vector_type(4))) _Float16 half4;  // 4 f16 (8B)
typedef __attribute__((ext_vector_type(4))) float float4v;   // 4 fp32

__device__ __forceinline__ half8 h8s(half8 a, _Float16 c) { return a * c; }

// Raw workgroup barrier: LDS-visibility only (lgkmcnt(0)), does NOT drain vmcnt.
// This lets register-destined global prefetch loads stay in flight across the
// barrier (hipcc's __syncthreads would force s_waitcnt vmcnt(0)).
// The trailing empty asm keeps later memory ops from hoisting above the barrier.
__device__ __forceinline__ void wg_barrier() {
    asm volatile("s_waitcnt lgkmcnt(0)" ::: "memory");
    __builtin_amdgcn_s_barrier();
    asm volatile("" ::: "memory");
}

// ---------------- self-connection: 8 nodes/block, branchless ----------------
__global__ __launch_bounds__(256) void sc_kernel(const float* __restrict__ x,
                                                 const float* __restrict__ L0,
                                                 const float* __restrict__ L1,
                                                 float* __restrict__ out) {
    __shared__ float l0[256], l1[256];
    __shared__ float xs[512];
    const int t = threadIdx.x;
    l0[t] = L0[t];
    l1[t] = L1[t];
    const int base = blockIdx.x * 512;           // 3125 blocks * 8 nodes * 64
    if (t < 128) *(float4v*)(&xs[t * 4]) = *(const float4v*)(x + base + t * 4);
    __syncthreads();
    #pragma unroll
    for (int i = 0; i < 2; ++i) {
        const int elem = t + 256 * i;            // 0..511
        const int j = elem & 63;
        const float* xr = &xs[elem & ~63];       // node-local row
        const bool is0 = j < 16;
        const int q = j - 16;
        const int v = is0 ? j : q / 3;
        const int k = is0 ? 0 : q - 3 * v;
        const float* mat = is0 ? l0 : l1;
        const int ab = is0 ? 0 : 16 + k;         // a index = ab + as*u
        const int as = is0 ? 1 : 3;
        float s = 0.f;
        #pragma unroll
        for (int u = 0; u < 16; ++u) s = fmaf(xr[ab + as * u], mat[u * 16 + v], s);
        out[base + elem] = 0.25f * s;            // 1/sqrt(MUL)
    }
}

// ---------------- edge kernel: 12 waves (768 thr), balanced planes, pipelined ----------------
// Wave w (0..11): plane = w>>1 in [0,6), uh = w&1. chunk(plane) = min(plane,3).
// Every wave: 2 m-tiles x 8 u x 2 kf = 32 MFMAs (was 32/96 imbalanced).
// Per tile: B1 -> [prefetch issue + coef/h] -> B2 -> [frags + MFMA + xch] -> B3
//           -> [combine + atomics + stage next tile from regs] -> loop.
// Prefetch global loads issued at phase A are consumed (stored to LDS) at phase C;
// raw barriers keep them in flight across B2/B3 (latency hidden under MFMA).
__global__ __launch_bounds__(768, 6) void edge_kernel(
    const float* __restrict__ x, const float* __restrict__ edge_attr,
    const float* __restrict__ edge_length, const int* __restrict__ edge_src,
    const int* __restrict__ edge_dst, const float* __restrict__ W1,
    const float* __restrict__ W2, float* __restrict__ out) {

    const int t = threadIdx.x;
    const int w = t >> 6;             // wave id 0..11
    const int qm = t & 15;            // MFMA m/n index
    const int quad = (t >> 4) & 3;    // lane quad within wave
    const int plane = w >> 1;         // 0..5
    const int uh = w & 1;             // u-half
    const int chunk = plane < 3 ? plane : 3;

    __shared__ __attribute__((aligned(16))) _Float16 lds_h16[ET * 72];  // f16 h, stride 72
    __shared__ __attribute__((aligned(16))) float lds_xj[2][ET * 68];   // dbuf gathered x[src]
    __shared__ __attribute__((aligned(16))) float lds_cf[6 * PL];       // coef planes
    __shared__ __attribute__((aligned(16))) float lds_xch[12 * PL];     // term exchange
    __shared__ __attribute__((aligned(16))) float lds_w1t[64 * 8];      // W1^T [c][r]
    __shared__ __attribute__((aligned(16))) float lds_sh[2][ET * 4];    // dbuf edge_attr
    __shared__ float lds_len[2][ET];
    __shared__ int   lds_dst[2][ET];
    __shared__ int   lds_src[ET];     // src of NEXT tile (single buffer, see barriers)

    // ---- persistent B fragments: W2 chunk, u-half uh, pre-scaled f16 ----
    half8 bfr[8][2];
    {
        float scale = 0.0220970869f;                  // (1/sqrt(64)) * (1/sqrt(32))
        if (plane == 1) scale *= 0.5773502692f;       // INV_SQRT3 folded
        const int kr = quad * 8;
        #pragma unroll
        for (int up = 0; up < 8; ++up) {
            const int col = chunk * 256 + (uh * 8 + up) * 16 + qm;
            #pragma unroll
            for (int kf = 0; kf < 2; ++kf) {
                half8 f;
                #pragma unroll
                for (int j = 0; j < 8; ++j) {
                    const int k = kf * 32 + kr + j;
                    f[j] = (_Float16)(W2[k * 1024 + col] * scale);
                }
                bfr[up][kf] = f;
            }
        }
    }
    if (t < 512) { const int r = t >> 6, c = t & 63; lds_w1t[c * 8 + r] = W1[t]; }

    // ---- prologue: stage tile blockIdx.x into buffer 0 ----
    int T = blockIdx.x;
    if (t < ET) {
        const int e = T * ET + t;
        lds_src[t] = edge_src[e];
        lds_dst[0][t] = edge_dst[e];
        lds_len[0][t] = edge_length[e];
        const float4v ea = *(const float4v*)(edge_attr + 4 * e);
        lds_sh[0][t * 4 + 0] = ea[0]; lds_sh[0][t * 4 + 1] = ea[1];
        lds_sh[0][t * 4 + 2] = ea[2]; lds_sh[0][t * 4 + 3] = ea[3];
    }
    __syncthreads();
    {
        float4v r0;
        if (t < 512) {
            const int src = lds_src[t >> 4];
            r0 = *(const float4v*)(x + src * 64 + (t & 15) * 4);
        }
        __syncthreads();   // all lds_src reads done before overwrite (prologue only)
        int rs;
        if (t < ET) {
            const int Tn = (T + NBLK < NTILES) ? T + NBLK : T;
            rs = edge_src[Tn * ET + t];
        }
        if (t < 512) *(float4v*)(&lds_xj[0][(t >> 4) * 68 + (t & 15) * 4]) = r0;
        if (t < ET) lds_src[t] = rs;   // invariant: lds_src holds src(T+NBLK)
    }

    int p = 0;
    while (true) {
        wg_barrier();   // B1: staged buffers visible; prev-iter LDS reads retired
        const int Tn  = (T + NBLK < NTILES) ? T + NBLK : T;
        const int Tnn = (T + 2 * NBLK < NTILES) ? T + 2 * NBLK : Tn;

        // ---- phase A1: issue next-tile prefetch (consumed in phase C) ----
        float4v r_xj, r_ea; float r_len; int r_dst, r_src;
        if (t < 512) {
            const int src = lds_src[t >> 4];
            r_xj = *(const float4v*)(x + src * 64 + (t & 15) * 4);
        }
        if (t < ET) {
            const int en = Tn * ET + t;
            r_dst = edge_dst[en];
            r_len = edge_length[en];
            r_ea  = *(const float4v*)(edge_attr + 4 * en);
            r_src = edge_src[Tnn * ET + t];
        }

        // ---- phase A2: coef planes + h (t<512: e = t&31, u = t>>5) ----
        if (t < 512) {
            const int e = t & 31, u = t >> 5;
            const float* shp = &lds_sh[p][e * 4];
            const float sh0 = shp[0], s1x = shp[1], s1y = shp[2], s1z = shp[3];
            const float* xjp = &lds_xj[p][e * 68];
            const float xj0v = xjp[u];
            const float x0 = xjp[16 + 3 * u];
            const float x1 = xjp[17 + 3 * u];
            const float x2 = xjp[18 + 3 * u];
            lds_cf[0 * PL + e * 17 + u] = xj0v * sh0;
            lds_cf[1 * PL + e * 17 + u] = fmaf(x0, s1x, fmaf(x1, s1y, x2 * s1z));
            lds_cf[2 * PL + e * 17 + u] = xj0v;
            lds_cf[3 * PL + e * 17 + u] = x0 * sh0;
            lds_cf[4 * PL + e * 17 + u] = x1 * sh0;
            lds_cf[5 * PL + e * 17 + u] = x2 * sh0;
            // h = silu(radial @ W1 / sqrt(8)) for (e, c0..c0+3), stored f16
            const int c0 = u * 4;
            const float len = lds_len[p][e];
            float rad[8];
            #pragma unroll
            for (int r = 0; r < 8; ++r) {
                const float d = len - 0.7142857143f * (float)r;
                rad[r] = __expf(-0.5f * d * d);
            }
            half4 hv;
            #pragma unroll
            for (int i = 0; i < 4; ++i) {
                const float4v wA = *(const float4v*)(&lds_w1t[(c0 + i) * 8]);
                const float4v wB = *(const float4v*)(&lds_w1t[(c0 + i) * 8 + 4]);
                float s = rad[0] * wA[0] + rad[1] * wA[1] + rad[2] * wA[2] + rad[3] * wA[3]
                        + rad[4] * wB[0] + rad[5] * wB[1] + rad[6] * wB[2] + rad[7] * wB[3];
                s *= 0.3535533906f;
                hv[i] = (_Float16)(s / (1.f + __expf(-s)));
            }
            *(half4*)(&lds_h16[e * 72 + c0]) = hv;
        }
        wg_barrier();   // B2: cf/h visible (prefetch loads remain in flight)

        // ---- phase B: A fragments (direct f16 loads) + MFMA + xch ----
        half8 a0[2], a1[2];
        #pragma unroll
        for (int mt = 0; mt < 2; ++mt) {
            const _Float16* hrow = &lds_h16[(mt * 16 + qm) * 72];
            a0[mt] = *(const half8*)(hrow + quad * 8);
            a1[mt] = *(const half8*)(hrow + 32 + quad * 8);
        }
        float4v acc[2];
        acc[0] = (float4v){0.f, 0.f, 0.f, 0.f};
        acc[1] = (float4v){0.f, 0.f, 0.f, 0.f};
        #pragma unroll
        for (int up = 0; up < 8; ++up) {
            const int u = uh * 8 + up;
            #pragma unroll
            for (int mt = 0; mt < 2; ++mt) {
                const _Float16 c = (_Float16)lds_cf[plane * PL + (mt * 16 + qm) * 17 + u];
                acc[mt] = __builtin_amdgcn_mfma_f32_16x16x32_f16(h8s(a0[mt], c), bfr[up][0], acc[mt], 0, 0, 0);
                acc[mt] = __builtin_amdgcn_mfma_f32_16x16x32_f16(h8s(a1[mt], c), bfr[up][1], acc[mt], 0, 0, 0);
            }
        }
        {
            const int xp = (plane < 3) ? (plane * 2 + uh) : (6 + uh * 3 + (plane - 3));
            float* xb = &lds_xch[xp * PL];
            #pragma unroll
            for (int mt = 0; mt < 2; ++mt)
                #pragma unroll
                for (int r = 0; r < 4; ++r)
                    xb[(mt * 16 + quad * 4 + r) * 17 + qm] = acc[mt][r];
        }
        wg_barrier();   // B3: xch visible

        // ---- phase C: combine (one atomic per output elem) ----
        #pragma unroll
        for (int i = 0; i < 3; ++i) {
            const int idx = t + 768 * i;          // 2048 = 32 edges x 64 elems
            if (idx < 2048) {
                const int e = idx >> 6, j = idx & 63;
                float val;
                if (j < 16) {
                    val = (lds_xch[0 * PL + e * 17 + j] + lds_xch[1 * PL + e * 17 + j])
                        + (lds_xch[2 * PL + e * 17 + j] + lds_xch[3 * PL + e * 17 + j]);
                } else {
                    const int q = j - 16, v = q / 3, k = q - 3 * v;
                    const float s2 = lds_xch[4 * PL + e * 17 + v] + lds_xch[5 * PL + e * 17 + v];
                    const float s3 = lds_xch[(6 + k) * PL + e * 17 + v]
                                   + lds_xch[(9 + k) * PL + e * 17 + v];
                    val = fmaf(s2, lds_sh[p][e * 4 + 1 + k], s3);
                }
                atomicAdd(out + lds_dst[p][e] * 64 + j, val);
            }
        }

        // ---- stage next tile from prefetch regs (vmcnt wait happens here) ----
        T += NBLK;
        if (T >= NTILES) break;
        const int np = p ^ 1;
        if (t < 512) *(float4v*)(&lds_xj[np][(t >> 4) * 68 + (t & 15) * 4]) = r_xj;
        if (t < ET) {
            lds_dst[np][t] = r_dst;
            lds_len[np][t] = r_len;
            lds_sh[np][t * 4 + 0] = r_ea[0]; lds_sh[np][t * 4 + 1] = r_ea[1];
            lds_sh[np][t * 4 + 2] = r_ea[2]; lds_sh[np][t * 4 + 3] = r_ea[3];
            lds_src[t] = r_src;
        }
        p = np;
        // next-iteration B1 orders these writes before their readers
    }
}

extern "C" void kernel_launch(void* const* d_in, const int* in_sizes, int n_in,
                              void* d_out, int out_size, void* d_ws, size_t ws_size,
                              hipStream_t stream) {
    const float* x           = (const float*)d_in[0];
    const float* edge_attr   = (const float*)d_in[1];
    const float* edge_length = (const float*)d_in[2];
    const int*   edge_src    = (const int*)d_in[3];
    const int*   edge_dst    = (const int*)d_in[4];
    const float* W1          = (const float*)d_in[5];
    const float* W2          = (const float*)d_in[6];
    const float* L0          = (const float*)d_in[7];
    const float* L1          = (const float*)d_in[8];
    float* out = (float*)d_out;

    sc_kernel<<<N_NODES / 8, 256, 0, stream>>>(x, L0, L1, out);
    edge_kernel<<<NBLK, 768, 0, stream>>>(
        x, edge_attr, edge_length, edge_src, edge_dst, W1, W2, out);
}

// Round 2
// 310.267 us; speedup vs baseline: 1.0708x; 1.0708x over previous
//
#include <hip/hip_runtime.h>

// Problem constants
#define N_NODES 25000
#define N_EDGES 200000
// MUL=16, NUM_RADIAL=8, HIDDEN=64, WNUMEL=1024
// PATH_ALPHA=1/sqrt(32), INV_SQRT3=1/sqrt(3), scales folded into B-fragments.

constexpr int ET = 32;      // edges per tile
constexpr int NT = 5;       // tiles per block
constexpr int NBLK = 1250;  // 1250*5*32 = 200000 edges exactly

typedef __attribute__((ext_vector_type(8))) _Float16 half8;  // 8 f16 (4 VGPR)
typedef __attribute__((ext_vector_type(4))) float float4v;   // 4 fp32

__device__ __forceinline__ half8 h8s(half8 a, _Float16 c) { return a * c; }  // v_pk_mul_f16 x4

// ---------------- self-connection (fallback path only) ----------------
__global__ __launch_bounds__(256) void sc_kernel(const float* __restrict__ x,
                                                 const float* __restrict__ L0,
                                                 const float* __restrict__ L1,
                                                 float* __restrict__ out) {
    __shared__ float l0[256], l1[256];
    __shared__ float xs[4][68];
    const int t = threadIdx.x;
    l0[t] = L0[t];
    l1[t] = L1[t];
    const int g = t >> 6, j = t & 63;
    const int n = blockIdx.x * 4 + g;
    xs[g][j] = x[n * 64 + j];
    __syncthreads();
    float s = 0.f;
    if (j < 16) {
        #pragma unroll
        for (int u = 0; u < 16; ++u) s = fmaf(xs[g][u], l0[u * 16 + j], s);
    } else {
        const int q = j - 16, v = q / 3, k = q - 3 * v;
        #pragma unroll
        for (int u = 0; u < 16; ++u) s = fmaf(xs[g][16 + 3 * u + k], l1[u * 16 + v], s);
    }
    out[n * 64 + j] = 0.25f * s;   // 1/sqrt(MUL)
}

// ---------------- CSR-by-dst build ----------------
__global__ __launch_bounds__(256) void k_zero(int* __restrict__ cnt) {
    const int i = blockIdx.x * 256 + threadIdx.x;
    if (i < N_NODES) cnt[i] = 0;
}

__global__ __launch_bounds__(256) void k_hist(const int* __restrict__ edge_dst,
                                              int* __restrict__ cnt) {
    const int e = blockIdx.x * 256 + threadIdx.x;
    if (e < N_EDGES) atomicAdd(&cnt[edge_dst[e]], 1);
}

// one block, 1024 threads: exclusive scan of 25000 counts -> offs, cur
__global__ __launch_bounds__(1024) void k_scan(const int* __restrict__ cnt,
                                               int* __restrict__ offs,
                                               int* __restrict__ cur) {
    const int t = threadIdx.x;
    const int base = t * 25;                   // 1024*25 = 25600 >= 25000
    int local[25];
    int s = 0;
    #pragma unroll
    for (int i = 0; i < 25; ++i) {
        const int idx = base + i;
        const int c = (idx < N_NODES) ? cnt[idx] : 0;
        local[i] = c;
        s += c;
    }
    __shared__ int ps[1024];
    ps[t] = s;
    __syncthreads();
    for (int off = 1; off < 1024; off <<= 1) {   // Hillis-Steele inclusive scan
        int v = 0;
        if (t >= off) v = ps[t - off];
        __syncthreads();
        ps[t] += v;
        __syncthreads();
    }
    int run = ps[t] - s;                         // exclusive base for this thread
    #pragma unroll
    for (int i = 0; i < 25; ++i) {
        const int idx = base + i;
        if (idx < N_NODES) {
            offs[idx] = run;
            cur[idx] = run;
            run += local[i];
        }
    }
}

__global__ __launch_bounds__(256) void k_scatter(const int* __restrict__ edge_dst,
                                                 int* __restrict__ cur,
                                                 int* __restrict__ order) {
    const int e = blockIdx.x * 256 + threadIdx.x;
    if (e < N_EDGES) {
        const int pos = atomicAdd(&cur[edge_dst[e]], 1);
        order[pos] = e;
    }
}

// ---------------- edge kernel: round-0 structure; MODE 1 stores m_ij to ws ----------------
// 512 threads, 8 waves. Wave w: prog = w>>1, uh = w&1 (u in [uh*8, uh*8+8)).
//   C[e][v] = sum_u coef[e][u] * sum_c h[e][c]*W2[c][u*16+v]*scale
// Coef planes: 0: xj0*sh0 | 1: b1 | 2: xj0 | 3+k: xj1[.,k]*sh0
template<int TO_WS>
__global__ __launch_bounds__(512, 4) void edge_kernel(
    const float* __restrict__ x, const float* __restrict__ edge_attr,
    const float* __restrict__ edge_length, const int* __restrict__ edge_src,
    const int* __restrict__ edge_dst, const float* __restrict__ W1,
    const float* __restrict__ W2, float* __restrict__ outp) {

    const int t = threadIdx.x;
    const int w = t >> 6;             // wave id 0..7
    const int prog = w >> 1;          // which 16x16-block family of w2
    const int uh = w & 1;             // u-half
    const int qm = t & 15;            // MFMA m/n index
    const int quad = (t >> 4) & 3;    // lane quad within wave

    __shared__ __attribute__((aligned(16))) float lds_h[ET * 72];    // fp32 h, stride 72
    __shared__ __attribute__((aligned(16))) float lds_xj[ET * 68];   // gathered x[src], stride 68
    __shared__ __attribute__((aligned(16))) float lds_cf[6 * ET * 17];  // coef planes [pl][e*17+u]
    __shared__ __attribute__((aligned(16))) float lds_xch[12 * ET * 17];// term exchange [pl][e*17+v]
    __shared__ __attribute__((aligned(16))) float lds_w1t[64 * 8];   // W1^T [c][r]
    __shared__ __attribute__((aligned(16))) float lds_sh[ET * 4];
    __shared__ float lds_len[ET];
    __shared__ int   lds_dst[ET];

    constexpr int PL = ET * 17;       // plane stride (544)

    // ---- persistent B fragments: W2 block `prog`, u-half `uh`, pre-scaled f16 ----
    half8 bfr[8][2];
    {
        float scale = 0.0220970869f;                  // (1/sqrt(64)) * (1/sqrt(32))
        if (prog == 1) scale *= 0.5773502692f;        // INV_SQRT3 folded
        const int kr = quad * 8;
        #pragma unroll
        for (int up = 0; up < 8; ++up) {
            const int col = prog * 256 + (uh * 8 + up) * 16 + qm;
            #pragma unroll
            for (int kf = 0; kf < 2; ++kf) {
                half8 f;
                #pragma unroll
                for (int j = 0; j < 8; ++j) {
                    const int k = kf * 32 + kr + j;
                    f[j] = (_Float16)(W2[k * 1024 + col] * scale);
                }
                bfr[up][kf] = f;
            }
        }
    }
    // W1 -> LDS transposed [c][r]
    {
        const int r = t >> 6, c = t & 63;
        lds_w1t[c * 8 + r] = W1[t];
    }

    for (int tl = 0; tl < NT; ++tl) {
        const int e0 = (blockIdx.x * NT + tl) * ET;
        __syncthreads();   // orders prev-tile combine reads before re-staging

        // ---- phase 1: meta + xj gather ----
        if (t < ET) {
            if constexpr (!TO_WS) lds_dst[t] = edge_dst[e0 + t];
            lds_len[t] = edge_length[e0 + t];
            const float4v ea = *(const float4v*)(edge_attr + 4 * (e0 + t));
            lds_sh[t * 4 + 0] = ea[0]; lds_sh[t * 4 + 1] = ea[1];
            lds_sh[t * 4 + 2] = ea[2]; lds_sh[t * 4 + 3] = ea[3];
        }
        {
            const int e_loc = t >> 4;                 // 32 edges x 16 threads
            const int src = edge_src[e0 + e_loc];     // 16-thread-uniform
            const int c4 = (t & 15) * 4;
            *(float4v*)(&lds_xj[e_loc * 68 + c4]) = *(const float4v*)(x + src * 64 + c4);
        }
        __syncthreads();

        // ---- phase 2: coef planes + h (e = t&31, u = t>>5) ----
        {
            const int e = t & 31, u = t >> 5;
            const float sh0 = lds_sh[e * 4];
            const float s1x = lds_sh[e * 4 + 1];
            const float s1y = lds_sh[e * 4 + 2];
            const float s1z = lds_sh[e * 4 + 3];
            const float xj0v = lds_xj[e * 68 + u];
            const float x0 = lds_xj[e * 68 + 16 + 3 * u];
            const float x1 = lds_xj[e * 68 + 17 + 3 * u];
            const float x2 = lds_xj[e * 68 + 18 + 3 * u];
            lds_cf[0 * PL + e * 17 + u] = xj0v * sh0;
            lds_cf[1 * PL + e * 17 + u] = fmaf(x0, s1x, fmaf(x1, s1y, x2 * s1z));
            lds_cf[2 * PL + e * 17 + u] = xj0v;
            lds_cf[3 * PL + e * 17 + u] = x0 * sh0;
            lds_cf[4 * PL + e * 17 + u] = x1 * sh0;
            lds_cf[5 * PL + e * 17 + u] = x2 * sh0;
            // h = silu(radial @ W1 / sqrt(8)) for (e, c0..c0+3)
            const int c0 = u * 4;
            const float len = lds_len[e];
            float rad[8];
            #pragma unroll
            for (int r = 0; r < 8; ++r) {
                const float d = len - 0.7142857143f * (float)r;
                rad[r] = __expf(-0.5f * d * d);
            }
            float4v hv;
            #pragma unroll
            for (int i = 0; i < 4; ++i) {
                const float4v wA = *(const float4v*)(&lds_w1t[(c0 + i) * 8]);
                const float4v wB = *(const float4v*)(&lds_w1t[(c0 + i) * 8 + 4]);
                float s = rad[0] * wA[0] + rad[1] * wA[1] + rad[2] * wA[2] + rad[3] * wA[3]
                        + rad[4] * wB[0] + rad[5] * wB[1] + rad[6] * wB[2] + rad[7] * wB[3];
                s *= 0.3535533906f;
                hv[i] = s / (1.f + __expf(-s));
            }
            *(float4v*)(&lds_h[e * 72 + c0]) = hv;
        }
        __syncthreads();

        // ---- phase 3: A fragments for both m-tiles (f16) ----
        half8 ah0[2], ah1[2];
        #pragma unroll
        for (int mt = 0; mt < 2; ++mt) {
            const float* hrow = &lds_h[(mt * 16 + qm) * 72];
            const float4v fa = *(const float4v*)(hrow + quad * 8);
            const float4v fb = *(const float4v*)(hrow + quad * 8 + 4);
            const float4v fc = *(const float4v*)(hrow + 32 + quad * 8);
            const float4v fd = *(const float4v*)(hrow + 32 + quad * 8 + 4);
            #pragma unroll
            for (int j = 0; j < 4; ++j) {
                ah0[mt][j]     = (_Float16)fa[j];
                ah0[mt][4 + j] = (_Float16)fb[j];
                ah1[mt][j]     = (_Float16)fc[j];
                ah1[mt][4 + j] = (_Float16)fd[j];
            }
        }

        // ---- MFMA with per-u coef-scaled A ----
        if (prog < 3) {
            float4v acc[2];
            acc[0] = (float4v){0.f, 0.f, 0.f, 0.f};
            acc[1] = (float4v){0.f, 0.f, 0.f, 0.f};
            #pragma unroll
            for (int up = 0; up < 8; ++up) {
                #pragma unroll
                for (int mt = 0; mt < 2; ++mt) {
                    const _Float16 c = (_Float16)lds_cf[prog * PL + (mt * 16 + qm) * 17 + (uh * 8 + up)];
                    acc[mt] = __builtin_amdgcn_mfma_f32_16x16x32_f16(h8s(ah0[mt], c), bfr[up][0], acc[mt], 0, 0, 0);
                    acc[mt] = __builtin_amdgcn_mfma_f32_16x16x32_f16(h8s(ah1[mt], c), bfr[up][1], acc[mt], 0, 0, 0);
                }
            }
            float* xb = &lds_xch[w * PL];
            #pragma unroll
            for (int mt = 0; mt < 2; ++mt)
                #pragma unroll
                for (int r = 0; r < 4; ++r)
                    xb[(mt * 16 + quad * 4 + r) * 17 + qm] = acc[mt][r];
        } else {
            float4v a3[2][3];
            #pragma unroll
            for (int mt = 0; mt < 2; ++mt)
                #pragma unroll
                for (int k = 0; k < 3; ++k) a3[mt][k] = (float4v){0.f, 0.f, 0.f, 0.f};
            #pragma unroll
            for (int up = 0; up < 8; ++up) {
                #pragma unroll
                for (int mt = 0; mt < 2; ++mt) {
                    #pragma unroll
                    for (int k = 0; k < 3; ++k) {
                        const _Float16 c = (_Float16)lds_cf[(3 + k) * PL + (mt * 16 + qm) * 17 + (uh * 8 + up)];
                        a3[mt][k] = __builtin_amdgcn_mfma_f32_16x16x32_f16(h8s(ah0[mt], c), bfr[up][0], a3[mt][k], 0, 0, 0);
                        a3[mt][k] = __builtin_amdgcn_mfma_f32_16x16x32_f16(h8s(ah1[mt], c), bfr[up][1], a3[mt][k], 0, 0, 0);
                    }
                }
            }
            #pragma unroll
            for (int k = 0; k < 3; ++k) {
                float* xb = &lds_xch[(6 + uh * 3 + k) * PL];
                #pragma unroll
                for (int mt = 0; mt < 2; ++mt)
                    #pragma unroll
                    for (int r = 0; r < 4; ++r)
                        xb[(mt * 16 + quad * 4 + r) * 17 + qm] = a3[mt][k][r];
            }
        }
        __syncthreads();

        // ---- combine ----
        if constexpr (TO_WS) {
            // one float4 store per thread: e = t>>4, j0 = (t&15)*4
            const int e = t >> 4;
            const int j0 = (t & 15) * 4;
            float4v vv;
            if (j0 < 16) {
                #pragma unroll
                for (int jj = 0; jj < 4; ++jj) {
                    const int j = j0 + jj;
                    vv[jj] = (lds_xch[0 * PL + e * 17 + j] + lds_xch[1 * PL + e * 17 + j])
                           + (lds_xch[2 * PL + e * 17 + j] + lds_xch[3 * PL + e * 17 + j]);
                }
            } else {
                #pragma unroll
                for (int jj = 0; jj < 4; ++jj) {
                    const int j = j0 + jj;
                    const int q = j - 16, v = q / 3, k = q - 3 * v;
                    const float s2 = lds_xch[4 * PL + e * 17 + v] + lds_xch[5 * PL + e * 17 + v];
                    const float s3 = lds_xch[(6 + k) * PL + e * 17 + v]
                                   + lds_xch[(9 + k) * PL + e * 17 + v];
                    vv[jj] = fmaf(s2, lds_sh[e * 4 + 1 + k], s3);
                }
            }
            *(float4v*)(outp + (size_t)(e0 + e) * 64 + j0) = vv;
        } else {
            #pragma unroll
            for (int i = 0; i < 4; ++i) {
                const int idx = t + 512 * i;          // 2048 = 32 edges x 64 elems
                const int e = idx >> 6, j = idx & 63;
                float val;
                if (j < 16) {
                    val = (lds_xch[0 * PL + e * 17 + j] + lds_xch[1 * PL + e * 17 + j])
                        + (lds_xch[2 * PL + e * 17 + j] + lds_xch[3 * PL + e * 17 + j]);
                } else {
                    const int q = j - 16, v = q / 3, k = q - 3 * v;
                    const float s2 = lds_xch[4 * PL + e * 17 + v] + lds_xch[5 * PL + e * 17 + v];
                    const float s3 = lds_xch[(6 + k) * PL + e * 17 + v]
                                   + lds_xch[(9 + k) * PL + e * 17 + v];
                    val = fmaf(s2, lds_sh[e * 4 + 1 + k], s3);
                }
                atomicAdd(outp + lds_dst[e] * 64 + j, val);
            }
        }
    }
}

// ---------------- per-node reduce + self-connection, plain stores ----------------
__global__ __launch_bounds__(256) void k_reduce(
    const float* __restrict__ x, const float* __restrict__ L0,
    const float* __restrict__ L1, const float* __restrict__ ws_m,
    const int* __restrict__ offs, const int* __restrict__ cur,
    const int* __restrict__ order, float* __restrict__ out) {

    __shared__ float l0[256], l1[256];
    const int t = threadIdx.x;
    l0[t] = L0[t];
    l1[t] = L1[t];
    __syncthreads();

    const int n = blockIdx.x * 4 + (t >> 6);       // 6250 blocks x 4 nodes = 25000
    const int lane = t & 63;
    const float xv = x[n * 64 + lane];

    // self-connection via wave shuffles (x row lives across the 64 lanes)
    const bool is0 = lane < 16;
    const int q = lane - 16;
    const int v = is0 ? lane : q / 3;
    const int k = is0 ? 0 : q - 3 * v;
    const float* mat = is0 ? l0 : l1;
    float s = 0.f;
    #pragma unroll
    for (int u = 0; u < 16; ++u) {
        const int sel = is0 ? u : 16 + 3 * u + k;
        const float a = __shfl(xv, sel);
        s = fmaf(a, mat[u * 16 + v], s);
    }
    float acc = 0.25f * s;                         // 1/sqrt(MUL)

    // sum this node's edge messages (rows are 256B contiguous, coalesced)
    int i = offs[n];
    const int e_end = cur[n];                      // offs[n] + count[n]
    for (; i + 2 <= e_end; i += 2) {
        const int ea = order[i], eb = order[i + 1];
        const float va = ws_m[(size_t)ea * 64 + lane];
        const float vb = ws_m[(size_t)eb * 64 + lane];
        acc += va + vb;
    }
    if (i < e_end) acc += ws_m[(size_t)order[i] * 64 + lane];

    out[n * 64 + lane] = acc;
}

extern "C" void kernel_launch(void* const* d_in, const int* in_sizes, int n_in,
                              void* d_out, int out_size, void* d_ws, size_t ws_size,
                              hipStream_t stream) {
    const float* x           = (const float*)d_in[0];
    const float* edge_attr   = (const float*)d_in[1];
    const float* edge_length = (const float*)d_in[2];
    const int*   edge_src    = (const int*)d_in[3];
    const int*   edge_dst    = (const int*)d_in[4];
    const float* W1          = (const float*)d_in[5];
    const float* W2          = (const float*)d_in[6];
    const float* L0          = (const float*)d_in[7];
    const float* L1          = (const float*)d_in[8];
    float* out = (float*)d_out;

    const size_t WS_M = (size_t)N_EDGES * 64;      // floats
    const size_t need = WS_M * 4 + (size_t)(3 * N_NODES + N_EDGES) * 4 + 256;

    if (ws_size >= need) {
        float* ws_m  = (float*)d_ws;
        int*   cnt   = (int*)(ws_m + WS_M);
        int*   offs  = cnt + N_NODES;
        int*   cur   = offs + N_NODES;
        int*   order = cur + N_NODES;

        k_zero<<<(N_NODES + 255) / 256, 256, 0, stream>>>(cnt);
        k_hist<<<(N_EDGES + 255) / 256, 256, 0, stream>>>(edge_dst, cnt);
        k_scan<<<1, 1024, 0, stream>>>(cnt, offs, cur);
        k_scatter<<<(N_EDGES + 255) / 256, 256, 0, stream>>>(edge_dst, cur, order);
        edge_kernel<1><<<NBLK, 512, 0, stream>>>(
            x, edge_attr, edge_length, edge_src, edge_dst, W1, W2, ws_m);
        k_reduce<<<N_NODES / 4, 256, 0, stream>>>(x, L0, L1, ws_m, offs, cur, order, out);
    } else {
        // fallback: original atomic path
        sc_kernel<<<N_NODES / 4, 256, 0, stream>>>(x, L0, L1, out);
        edge_kernel<0><<<NBLK, 512, 0, stream>>>(
            x, edge_attr, edge_length, edge_src, edge_dst, W1, W2, out);
    }
}